// Round 2
// baseline (2390.342 us; speedup 1.0000x reference)
//
#include <hip/hip_runtime.h>
#include <hip/hip_bf16.h>
#include <math.h>
#include <stdint.h>

#define HIDDEN 2048
#define NHEADS 6
#define HDIM 256
#define KDIM 1536
#define BATCH 2
#define SEQ 2048
#define BT (BATCH*SEQ)

typedef unsigned short u16;
typedef __attribute__((ext_vector_type(8))) short bf16x8;
typedef __attribute__((ext_vector_type(4))) float f32x4;

__device__ __forceinline__ u16 f2bf(float f) {
    unsigned u = __float_as_uint(f);
    u += 0x7FFFu + ((u >> 16) & 1u);          // round to nearest even
    return (u16)(u >> 16);
}
__device__ __forceinline__ float bf2f(u16 h) {
    return __uint_as_float(((unsigned)h) << 16);
}

// ---------------------------------------------------------------------------
// fp32 -> (bf16 hi, bf16 lo) split:  x ~= hi + lo  (lo captures next 8 bits)
// ---------------------------------------------------------------------------
__global__ __launch_bounds__(256)
void split_bf16(const float* __restrict__ src, u16* __restrict__ hi,
                u16* __restrict__ lo, int n4) {
    const int stride = gridDim.x * 256;
    for (int i = blockIdx.x * 256 + threadIdx.x; i < n4; i += stride) {
        const float4 f = ((const float4*)src)[i];
        ushort4 h, l;
        h.x = f2bf(f.x); l.x = f2bf(f.x - bf2f(h.x));
        h.y = f2bf(f.y); l.y = f2bf(f.y - bf2f(h.y));
        h.z = f2bf(f.z); l.z = f2bf(f.z - bf2f(h.z));
        h.w = f2bf(f.w); l.w = f2bf(f.w - bf2f(h.w));
        ((ushort4*)hi)[i] = h;
        ((ushort4*)lo)[i] = l;
    }
}

// ---------------------------------------------------------------------------
// Split-bf16 MFMA GEMM:  C[M=4096, N] = A[M,K] @ B[N,K]^T  (3-term split)
// 128x128 tile, BK=64, 4 waves (64x64 each), global_load_lds staging with
// XOR slot swizzle (slot ^= row&7) applied on the *global source* address
// (linear LDS dest) and again on the ds_read side.
// grid.y packs multiple weight matrices: j = by/blocksPerW selects weight.
// ---------------------------------------------------------------------------
#define GBM 128
#define GBK 64

#define GLL(gp, lp) __builtin_amdgcn_global_load_lds( \
    (__attribute__((address_space(1))) void*)(gp), \
    (__attribute__((address_space(3))) void*)(lp), 16, 0, 0)

__global__ __launch_bounds__(256, 2)
void gemm_bf16_split(const u16* __restrict__ Ah, const u16* __restrict__ Al,
                     const u16* __restrict__ Bh0, const u16* __restrict__ Bl0,
                     float* __restrict__ C0, int K, int rowsPerW, int blocksPerW) {
    __shared__ u16 lAh[GBM * GBK];
    __shared__ u16 lAl[GBM * GBK];
    __shared__ u16 lBh[GBM * GBK];
    __shared__ u16 lBl[GBM * GBK];

    const int j  = blockIdx.y / blocksPerW;
    const int ny = blockIdx.y % blocksPerW;
    const int m0 = blockIdx.x * GBM;
    const int n0 = ny * GBM;
    const u16* Bh = Bh0 + (size_t)j * rowsPerW * K;
    const u16* Bl = Bl0 + (size_t)j * rowsPerW * K;
    float* C = C0 + (size_t)j * (size_t)BT * rowsPerW;

    const int tid = threadIdx.x;
    const int wv  = tid >> 6;
    const int ln  = tid & 63;
    const int lr8 = ln >> 3;               // row within 8-row chunk
    const int lsl = (ln & 7) ^ lr8;        // pre-swizzled source slot

    // staging pointers: 4 chunks (of 8 rows x 128B) per wave per buffer
    const u16* pAh[4]; const u16* pAl[4]; const u16* pBh[4]; const u16* pBl[4];
    u16* dAh[4]; u16* dAl[4]; u16* dBh[4]; u16* dBl[4];
    #pragma unroll
    for (int u = 0; u < 4; ++u) {
        const int c = wv * 4 + u;
        const size_t ra = (size_t)(m0 + c * 8 + lr8) * K + (size_t)lsl * 8;
        const size_t rb = (size_t)(n0 + c * 8 + lr8) * K + (size_t)lsl * 8;
        pAh[u] = Ah + ra; pAl[u] = Al + ra;
        pBh[u] = Bh + rb; pBl[u] = Bl + rb;
        dAh[u] = &lAh[c * 512]; dAl[u] = &lAl[c * 512];
        dBh[u] = &lBh[c * 512]; dBl[u] = &lBl[c * 512];
    }

    const int lane15 = ln & 15;
    const int l16 = ln >> 4;               // 0..3 (k-slot within MFMA)
    const int wm = (wv >> 1) * 64;
    const int wn = (wv & 1) * 64;
    const int rA = wm + lane15;            // +mi*16 keeps rA&7 invariant
    const int rB = wn + lane15;
    const int xA = rA & 7;
    const int xB = rB & 7;

    f32x4 acc[4][4] = {};

    for (int k0 = 0; k0 < K; k0 += GBK) {
        #pragma unroll
        for (int u = 0; u < 4; ++u) {
            GLL(pAh[u] + k0, dAh[u]);
            GLL(pAl[u] + k0, dAl[u]);
            GLL(pBh[u] + k0, dBh[u]);
            GLL(pBl[u] + k0, dBl[u]);
        }
        __syncthreads();                    // drains vmcnt before barrier
        #pragma unroll
        for (int kh = 0; kh < 2; ++kh) {
            bf16x8 a_h[4], a_l[4], b_h[4], b_l[4];
            #pragma unroll
            for (int mi = 0; mi < 4; ++mi) {
                const int off = (rA + mi * 16) * GBK + ((((kh << 2) | l16)) ^ xA) * 8;
                a_h[mi] = *(const bf16x8*)&lAh[off];
                a_l[mi] = *(const bf16x8*)&lAl[off];
            }
            #pragma unroll
            for (int ni = 0; ni < 4; ++ni) {
                const int off = (rB + ni * 16) * GBK + ((((kh << 2) | l16)) ^ xB) * 8;
                b_h[ni] = *(const bf16x8*)&lBh[off];
                b_l[ni] = *(const bf16x8*)&lBl[off];
            }
            #pragma unroll
            for (int mi = 0; mi < 4; ++mi)
                #pragma unroll
                for (int ni = 0; ni < 4; ++ni) {
                    acc[mi][ni] = __builtin_amdgcn_mfma_f32_16x16x32_bf16(a_h[mi], b_h[ni], acc[mi][ni], 0, 0, 0);
                    acc[mi][ni] = __builtin_amdgcn_mfma_f32_16x16x32_bf16(a_h[mi], b_l[ni], acc[mi][ni], 0, 0, 0);
                    acc[mi][ni] = __builtin_amdgcn_mfma_f32_16x16x32_bf16(a_l[mi], b_h[ni], acc[mi][ni], 0, 0, 0);
                }
        }
        __syncthreads();
    }

    #pragma unroll
    for (int mi = 0; mi < 4; ++mi)
        #pragma unroll
        for (int ni = 0; ni < 4; ++ni) {
            const int m = m0 + wm + mi * 16 + l16 * 4;
            const int n = n0 + wn + ni * 16 + lane15;
            #pragma unroll
            for (int r = 0; r < 4; ++r)
                C[(size_t)(m + r) * rowsPerW + n] = acc[mi][ni][r];
        }
}

// ---------------------------------------------------------------------------
// beta = sigmoid(x @ Wb^T), g = -exp(A_log)*softplus(x @ Wa^T + dt_bias)
// ---------------------------------------------------------------------------
__global__ __launch_bounds__(256)
void beta_g_kernel(const float* __restrict__ x, const float* __restrict__ Wb,
                   const float* __restrict__ Wa, const float* __restrict__ A_log,
                   const float* __restrict__ dt_bias,
                   float* __restrict__ beta, float* __restrict__ g) {
    const int bt = blockIdx.x;
    __shared__ float xs[HIDDEN];
    const int tid = threadIdx.x;
    for (int i = tid; i < HIDDEN; i += 256) xs[i] = x[(long)bt * HIDDEN + i];
    __syncthreads();
    const int w = tid >> 6, l = tid & 63;
    #pragma unroll
    for (int r = 0; r < 3; ++r) {
        const int dj = w * 3 + r;  // 0..11
        const float* Wrow = (dj < 6) ? (Wb + dj * HIDDEN) : (Wa + (dj - 6) * HIDDEN);
        float s = 0.f;
        for (int i = l; i < HIDDEN; i += 64) s += xs[i] * Wrow[i];
        s += __shfl_xor(s, 1);  s += __shfl_xor(s, 2);  s += __shfl_xor(s, 4);
        s += __shfl_xor(s, 8);  s += __shfl_xor(s, 16); s += __shfl_xor(s, 32);
        if (l == 0) {
            if (dj < 6) {
                beta[bt * NHEADS + dj] = 1.f / (1.f + expf(-s));
            } else {
                const int h = dj - 6;
                const float z = s + dt_bias[h];
                const float sp = fmaxf(z, 0.f) + log1pf(expf(-fabsf(z)));
                g[bt * NHEADS + h] = -expf(A_log[h]) * sp;
            }
        }
    }
}

// ---------------------------------------------------------------------------
// causal depthwise conv (K=4) + SiLU, optional per-head L2 norm.
// ---------------------------------------------------------------------------
__global__ __launch_bounds__(256)
void conv_silu_norm(const float* __restrict__ raw, const float* __restrict__ cw,
                    float* __restrict__ outp, int do_norm) {
    const int bt = blockIdx.x;
    const int h  = blockIdx.y;
    const int t  = bt & (SEQ - 1);
    const int tid = threadIdx.x;
    const int c = h * HDIM + tid;
    const float4 w4 = *(const float4*)(cw + (long)c * 4);
    const float* rp = raw + (long)bt * KDIM + c;
    float y;
    if (t >= 3) {
        y = rp[-3 * KDIM] * w4.x + rp[-2 * KDIM] * w4.y + rp[-KDIM] * w4.z + rp[0] * w4.w;
    } else {
        y = rp[0] * w4.w;
        if (t >= 1) y += rp[-KDIM] * w4.z;
        if (t >= 2) y += rp[-2 * KDIM] * w4.y;
    }
    y = y / (1.f + expf(-y));  // SiLU
    if (do_norm) {
        float s = y * y;
        s += __shfl_xor(s, 1);  s += __shfl_xor(s, 2);  s += __shfl_xor(s, 4);
        s += __shfl_xor(s, 8);  s += __shfl_xor(s, 16); s += __shfl_xor(s, 32);
        __shared__ float ps[4];
        if ((tid & 63) == 0) ps[tid >> 6] = s;
        __syncthreads();
        const float tot = ps[0] + ps[1] + ps[2] + ps[3];
        y *= rsqrtf(tot + 1e-6f);
    }
    outp[(long)bt * KDIM + c] = y;
}

// ---------------------------------------------------------------------------
// Sequential gated delta-rule scan, split by state columns.
// grid (12, 16): (b*H+h, v-slice of 16 cols). 256 threads = 4 waves.
// ---------------------------------------------------------------------------
__global__ __launch_bounds__(256)
void scan_kernel(const float* __restrict__ q, const float* __restrict__ k,
                 const float* __restrict__ v, const float* __restrict__ g,
                 const float* __restrict__ beta, float* __restrict__ o) {
    const int bh = blockIdx.x;
    const int b = bh / NHEADS, h = bh % NHEADS;
    const int tid = threadIdx.x;
    const int w = tid >> 6, l = tid & 63;
    const int col = blockIdx.y * 16 + w * 4 + (l & 3);
    const int kg = l >> 2;
    const float scale = 0.0625f;           // 256^-0.5
    float S[16] = {};

    const long head_off = (long)h * HDIM;
    for (int t = 0; t < SEQ; ++t) {
        const long bt = (long)b * SEQ + t;
        const float* kp = k + bt * KDIM + head_off + kg * 16;
        const float* qp = q + bt * KDIM + head_off + kg * 16;
        const float eg  = expf(g[bt * NHEADS + h]);
        const float bta = beta[bt * NHEADS + h];
        const float vc  = v[bt * KDIM + head_off + col];
        float4 k0 = *(const float4*)(kp + 0);
        float4 k1 = *(const float4*)(kp + 4);
        float4 k2 = *(const float4*)(kp + 8);
        float4 k3 = *(const float4*)(kp + 12);
        float ks[16] = {k0.x,k0.y,k0.z,k0.w, k1.x,k1.y,k1.z,k1.w,
                        k2.x,k2.y,k2.z,k2.w, k3.x,k3.y,k3.z,k3.w};
        float kv = 0.f;
        #pragma unroll
        for (int jj = 0; jj < 16; ++jj) { S[jj] *= eg; kv += ks[jj] * S[jj]; }
        kv += __shfl_xor(kv, 4); kv += __shfl_xor(kv, 8);
        kv += __shfl_xor(kv, 16); kv += __shfl_xor(kv, 32);
        const float u = bta * (vc - kv);
        float4 q0 = *(const float4*)(qp + 0);
        float4 q1 = *(const float4*)(qp + 4);
        float4 q2 = *(const float4*)(qp + 8);
        float4 q3 = *(const float4*)(qp + 12);
        float qs[16] = {q0.x,q0.y,q0.z,q0.w, q1.x,q1.y,q1.z,q1.w,
                        q2.x,q2.y,q2.z,q2.w, q3.x,q3.y,q3.z,q3.w};
        float op = 0.f;
        #pragma unroll
        for (int jj = 0; jj < 16; ++jj) { S[jj] += ks[jj] * u; op += qs[jj] * S[jj]; }
        op += __shfl_xor(op, 4); op += __shfl_xor(op, 8);
        op += __shfl_xor(op, 16); op += __shfl_xor(op, 32);
        if (kg == 0) o[bt * KDIM + head_off + col] = op * scale;
    }
}

// ---------------------------------------------------------------------------
// o = rmsnorm(o)*w * silu(gate)
// ---------------------------------------------------------------------------
__global__ __launch_bounds__(256)
void norm_gate(const float* __restrict__ o, const float* __restrict__ gate,
               const float* __restrict__ nw, float* __restrict__ on) {
    const int bt = blockIdx.x, h = blockIdx.y, d = threadIdx.x;
    const long idx = (long)bt * KDIM + h * HDIM + d;
    const float ov = o[idx];
    float s = ov * ov;
    s += __shfl_xor(s, 1);  s += __shfl_xor(s, 2);  s += __shfl_xor(s, 4);
    s += __shfl_xor(s, 8);  s += __shfl_xor(s, 16); s += __shfl_xor(s, 32);
    __shared__ float ps[4];
    if ((d & 63) == 0) ps[d >> 6] = s;
    __syncthreads();
    const float tot = ps[0] + ps[1] + ps[2] + ps[3];
    const float r = rsqrtf(tot * (1.f / HDIM) + 1e-5f);
    const float gv = gate[idx];
    on[idx] = ov * r * nw[d] * (gv / (1.f + expf(-gv)));
}

// ---------------------------------------------------------------------------
extern "C" void kernel_launch(void* const* d_in, const int* in_sizes, int n_in,
                              void* d_out, int out_size, void* d_ws, size_t ws_size,
                              hipStream_t stream) {
    const float* x       = (const float*)d_in[0];
    const float* Wq      = (const float*)d_in[1];
    const float* Wk      = (const float*)d_in[2];
    const float* Wv      = (const float*)d_in[3];
    const float* Wo      = (const float*)d_in[4];
    const float* Wb      = (const float*)d_in[5];
    const float* Wa      = (const float*)d_in[6];
    const float* Wg      = (const float*)d_in[7];
    const float* conv_q  = (const float*)d_in[8];
    const float* conv_k  = (const float*)d_in[9];
    const float* conv_v  = (const float*)d_in[10];
    const float* o_norm_w= (const float*)d_in[11];
    const float* A_log   = (const float*)d_in[12];
    const float* dt_bias = (const float*)d_in[13];
    float* out = (float*)d_out;

    // ---- workspace layout ----
    const size_t SZ  = (size_t)BT * KDIM;      // 6.29M  (proj output)
    const size_t XSZ = (size_t)BT * HIDDEN;    // 8.39M  (x)
    const size_t WSZ = (size_t)KDIM * HIDDEN;  // 3.15M  (one proj weight)
    float* ws   = (float*)d_ws;
    float* qraw = ws;
    float* kraw = qraw + SZ;
    float* vraw = kraw + SZ;
    float* graw = vraw + SZ;
    float* qn   = graw + SZ;
    float* kn   = qn + SZ;
    float* vn   = kn + SZ;
    float* beta = vn + SZ;                      // BT*NHEADS = 24576
    float* gdec = beta + (size_t)BT * NHEADS;
    u16* bs = (u16*)(gdec + (size_t)BT * NHEADS);
    u16* xh = bs;
    u16* xl = xh + XSZ;
    u16* wh = xl + XSZ;                         // Wq,Wk,Wv,Wg hi (4*WSZ)
    u16* wl = wh + 4 * WSZ;                     // lo
    // aliases (used after projections are consumed):
    u16* onh = bs;                              // onrm hi (SZ)
    u16* onl = onh + SZ;                        // onrm lo
    u16* woh = onl + SZ;                        // Wo hi (WSZ)
    u16* wol = woh + WSZ;                       // Wo lo
    float* obuf = qraw;                         // scan output (qraw dead)
    float* onrm = kraw;                         // normed output (kraw dead)

    dim3 blk(256);
    // ---- split inputs to bf16 hi/lo ----
    split_bf16<<<dim3(2048), blk, 0, stream>>>(x,  xh, xl, (int)(XSZ / 4));
    split_bf16<<<dim3(2048), blk, 0, stream>>>(Wq, wh + 0 * WSZ, wl + 0 * WSZ, (int)(WSZ / 4));
    split_bf16<<<dim3(2048), blk, 0, stream>>>(Wk, wh + 1 * WSZ, wl + 1 * WSZ, (int)(WSZ / 4));
    split_bf16<<<dim3(2048), blk, 0, stream>>>(Wv, wh + 2 * WSZ, wl + 2 * WSZ, (int)(WSZ / 4));
    split_bf16<<<dim3(2048), blk, 0, stream>>>(Wg, wh + 3 * WSZ, wl + 3 * WSZ, (int)(WSZ / 4));
    // ---- fused q/k/v/gate projections: grid.y = 4 weights x 12 n-blocks ----
    gemm_bf16_split<<<dim3(BT / GBM, 48), blk, 0, stream>>>(
        xh, xl, wh, wl, qraw, HIDDEN, KDIM, 12);
    // ---- beta / g ----
    beta_g_kernel<<<dim3(BT), blk, 0, stream>>>(x, Wb, Wa, A_log, dt_bias, beta, gdec);
    // ---- conv + silu (+ l2norm for q,k) ----
    conv_silu_norm<<<dim3(BT, NHEADS), blk, 0, stream>>>(qraw, conv_q, qn, 1);
    conv_silu_norm<<<dim3(BT, NHEADS), blk, 0, stream>>>(kraw, conv_k, kn, 1);
    conv_silu_norm<<<dim3(BT, NHEADS), blk, 0, stream>>>(vraw, conv_v, vn, 0);
    // ---- sequential delta-rule scan ----
    scan_kernel<<<dim3(BATCH * NHEADS, 16), blk, 0, stream>>>(qn, kn, vn, gdec, beta, obuf);
    // ---- rmsnorm * w * silu(gate) ----
    norm_gate<<<dim3(BT, NHEADS), blk, 0, stream>>>(obuf, graw, o_norm_w, onrm);
    // ---- output projection ----
    split_bf16<<<dim3(2048), blk, 0, stream>>>(onrm, onh, onl, (int)(SZ / 4));
    split_bf16<<<dim3(2048), blk, 0, stream>>>(Wo, woh, wol, (int)(WSZ / 4));
    gemm_bf16_split<<<dim3(BT / GBM, 16), blk, 0, stream>>>(
        onh, onl, woh, wol, out, KDIM, HIDDEN, 16);
}

// Round 4
// 1703.074 us; speedup vs baseline: 1.4035x; 1.4035x over previous
//
#include <hip/hip_runtime.h>
#include <hip/hip_bf16.h>
#include <math.h>
#include <stdint.h>

#define HIDDEN 2048
#define NHEADS 6
#define HDIM 256
#define KDIM 1536
#define BATCH 2
#define SEQ 2048
#define BT (BATCH*SEQ)

typedef unsigned short u16;
typedef __attribute__((ext_vector_type(8))) short bf16x8;
typedef __attribute__((ext_vector_type(4))) float f32x4;
typedef __attribute__((ext_vector_type(4))) float f4;

__device__ __forceinline__ u16 f2bf(float f) {
    unsigned u = __float_as_uint(f);
    u += 0x7FFFu + ((u >> 16) & 1u);          // round to nearest even
    return (u16)(u >> 16);
}
__device__ __forceinline__ float bf2f(u16 h) {
    return __uint_as_float(((unsigned)h) << 16);
}

// ---------------------------------------------------------------------------
// fp32 -> (bf16 hi, bf16 lo) split:  x ~= hi + lo  (lo captures next 8 bits)
// ---------------------------------------------------------------------------
__global__ __launch_bounds__(256)
void split_bf16(const float* __restrict__ src, u16* __restrict__ hi,
                u16* __restrict__ lo, int n4) {
    const int stride = gridDim.x * 256;
    for (int i = blockIdx.x * 256 + threadIdx.x; i < n4; i += stride) {
        const float4 f = ((const float4*)src)[i];
        ushort4 h, l;
        h.x = f2bf(f.x); l.x = f2bf(f.x - bf2f(h.x));
        h.y = f2bf(f.y); l.y = f2bf(f.y - bf2f(h.y));
        h.z = f2bf(f.z); l.z = f2bf(f.z - bf2f(h.z));
        h.w = f2bf(f.w); l.w = f2bf(f.w - bf2f(h.w));
        ((ushort4*)hi)[i] = h;
        ((ushort4*)lo)[i] = l;
    }
}

// ---------------------------------------------------------------------------
// Split-bf16 MFMA GEMM:  C[M=4096, N] = A[M,K] @ B[N,K]^T  (3-term split)
// 128x128 tile, BK=64, 4 waves, global_load_lds staging with XOR slot swizzle
// applied on the *global source* address (linear LDS dest) and on ds_read.
// ---------------------------------------------------------------------------
#define GBM 128
#define GBK 64

#define GLL(gp, lp) __builtin_amdgcn_global_load_lds( \
    (__attribute__((address_space(1))) void*)(gp), \
    (__attribute__((address_space(3))) void*)(lp), 16, 0, 0)

__global__ __launch_bounds__(256, 2)
void gemm_bf16_split(const u16* __restrict__ Ah, const u16* __restrict__ Al,
                     const u16* __restrict__ Bh0, const u16* __restrict__ Bl0,
                     float* __restrict__ C0, int K, int rowsPerW, int blocksPerW) {
    __shared__ u16 lAh[GBM * GBK];
    __shared__ u16 lAl[GBM * GBK];
    __shared__ u16 lBh[GBM * GBK];
    __shared__ u16 lBl[GBM * GBK];

    const int j  = blockIdx.y / blocksPerW;
    const int ny = blockIdx.y % blocksPerW;
    const int m0 = blockIdx.x * GBM;
    const int n0 = ny * GBM;
    const u16* Bh = Bh0 + (size_t)j * rowsPerW * K;
    const u16* Bl = Bl0 + (size_t)j * rowsPerW * K;
    float* C = C0 + (size_t)j * (size_t)BT * rowsPerW;

    const int tid = threadIdx.x;
    const int wv  = tid >> 6;
    const int ln  = tid & 63;
    const int lr8 = ln >> 3;               // row within 8-row chunk
    const int lsl = (ln & 7) ^ lr8;        // pre-swizzled source slot

    const u16* pAh[4]; const u16* pAl[4]; const u16* pBh[4]; const u16* pBl[4];
    u16* dAh[4]; u16* dAl[4]; u16* dBh[4]; u16* dBl[4];
    #pragma unroll
    for (int u = 0; u < 4; ++u) {
        const int c = wv * 4 + u;
        const size_t ra = (size_t)(m0 + c * 8 + lr8) * K + (size_t)lsl * 8;
        const size_t rb = (size_t)(n0 + c * 8 + lr8) * K + (size_t)lsl * 8;
        pAh[u] = Ah + ra; pAl[u] = Al + ra;
        pBh[u] = Bh + rb; pBl[u] = Bl + rb;
        dAh[u] = &lAh[c * 512]; dAl[u] = &lAl[c * 512];
        dBh[u] = &lBh[c * 512]; dBl[u] = &lBl[c * 512];
    }

    const int lane15 = ln & 15;
    const int l16 = ln >> 4;               // 0..3 (k-slot within MFMA)
    const int wm = (wv >> 1) * 64;
    const int wn = (wv & 1) * 64;
    const int rA = wm + lane15;
    const int rB = wn + lane15;
    const int xA = rA & 7;
    const int xB = rB & 7;

    f32x4 acc[4][4] = {};

    for (int k0 = 0; k0 < K; k0 += GBK) {
        #pragma unroll
        for (int u = 0; u < 4; ++u) {
            GLL(pAh[u] + k0, dAh[u]);
            GLL(pAl[u] + k0, dAl[u]);
            GLL(pBh[u] + k0, dBh[u]);
            GLL(pBl[u] + k0, dBl[u]);
        }
        __syncthreads();
        #pragma unroll
        for (int kh = 0; kh < 2; ++kh) {
            bf16x8 a_h[4], a_l[4], b_h[4], b_l[4];
            #pragma unroll
            for (int mi = 0; mi < 4; ++mi) {
                const int off = (rA + mi * 16) * GBK + ((((kh << 2) | l16)) ^ xA) * 8;
                a_h[mi] = *(const bf16x8*)&lAh[off];
                a_l[mi] = *(const bf16x8*)&lAl[off];
            }
            #pragma unroll
            for (int ni = 0; ni < 4; ++ni) {
                const int off = (rB + ni * 16) * GBK + ((((kh << 2) | l16)) ^ xB) * 8;
                b_h[ni] = *(const bf16x8*)&lBh[off];
                b_l[ni] = *(const bf16x8*)&lBl[off];
            }
            #pragma unroll
            for (int mi = 0; mi < 4; ++mi)
                #pragma unroll
                for (int ni = 0; ni < 4; ++ni) {
                    acc[mi][ni] = __builtin_amdgcn_mfma_f32_16x16x32_bf16(a_h[mi], b_h[ni], acc[mi][ni], 0, 0, 0);
                    acc[mi][ni] = __builtin_amdgcn_mfma_f32_16x16x32_bf16(a_h[mi], b_l[ni], acc[mi][ni], 0, 0, 0);
                    acc[mi][ni] = __builtin_amdgcn_mfma_f32_16x16x32_bf16(a_l[mi], b_h[ni], acc[mi][ni], 0, 0, 0);
                }
        }
        __syncthreads();
    }

    #pragma unroll
    for (int mi = 0; mi < 4; ++mi)
        #pragma unroll
        for (int ni = 0; ni < 4; ++ni) {
            const int m = m0 + wm + mi * 16 + l16 * 4;
            const int n = n0 + wn + ni * 16 + lane15;
            #pragma unroll
            for (int r = 0; r < 4; ++r)
                C[(size_t)(m + r) * rowsPerW + n] = acc[mi][ni][r];
        }
}

// ---------------------------------------------------------------------------
// beta = sigmoid(x @ Wb^T), eg = exp(-exp(A_log)*softplus(x @ Wa^T + dt_bias))
// Stores exp(g): keeps the transcendental OFF the scan's critical path.
// ---------------------------------------------------------------------------
__global__ __launch_bounds__(256)
void beta_g_kernel(const float* __restrict__ x, const float* __restrict__ Wb,
                   const float* __restrict__ Wa, const float* __restrict__ A_log,
                   const float* __restrict__ dt_bias,
                   float* __restrict__ beta, float* __restrict__ eg) {
    const int bt = blockIdx.x;
    __shared__ float xs[HIDDEN];
    const int tid = threadIdx.x;
    for (int i = tid; i < HIDDEN; i += 256) xs[i] = x[(long)bt * HIDDEN + i];
    __syncthreads();
    const int w = tid >> 6, l = tid & 63;
    #pragma unroll
    for (int r = 0; r < 3; ++r) {
        const int dj = w * 3 + r;  // 0..11
        const float* Wrow = (dj < 6) ? (Wb + dj * HIDDEN) : (Wa + (dj - 6) * HIDDEN);
        float s = 0.f;
        for (int i = l; i < HIDDEN; i += 64) s += xs[i] * Wrow[i];
        s += __shfl_xor(s, 1);  s += __shfl_xor(s, 2);  s += __shfl_xor(s, 4);
        s += __shfl_xor(s, 8);  s += __shfl_xor(s, 16); s += __shfl_xor(s, 32);
        if (l == 0) {
            if (dj < 6) {
                beta[bt * NHEADS + dj] = 1.f / (1.f + expf(-s));
            } else {
                const int h = dj - 6;
                const float z = s + dt_bias[h];
                const float sp = fmaxf(z, 0.f) + log1pf(expf(-fabsf(z)));
                eg[bt * NHEADS + h] = expf(-expf(A_log[h]) * sp);
            }
        }
    }
}

// ---------------------------------------------------------------------------
// causal depthwise conv (K=4) + SiLU, optional per-head L2 norm.
// ---------------------------------------------------------------------------
__global__ __launch_bounds__(256)
void conv_silu_norm(const float* __restrict__ raw, const float* __restrict__ cw,
                    float* __restrict__ outp, int do_norm) {
    const int bt = blockIdx.x;
    const int h  = blockIdx.y;
    const int t  = bt & (SEQ - 1);
    const int tid = threadIdx.x;
    const int c = h * HDIM + tid;
    const float4 w4 = *(const float4*)(cw + (long)c * 4);
    const float* rp = raw + (long)bt * KDIM + c;
    float y;
    if (t >= 3) {
        y = rp[-3 * KDIM] * w4.x + rp[-2 * KDIM] * w4.y + rp[-KDIM] * w4.z + rp[0] * w4.w;
    } else {
        y = rp[0] * w4.w;
        if (t >= 1) y += rp[-KDIM] * w4.z;
        if (t >= 2) y += rp[-2 * KDIM] * w4.y;
    }
    y = y / (1.f + expf(-y));  // SiLU
    if (do_norm) {
        float s = y * y;
        s += __shfl_xor(s, 1);  s += __shfl_xor(s, 2);  s += __shfl_xor(s, 4);
        s += __shfl_xor(s, 8);  s += __shfl_xor(s, 16); s += __shfl_xor(s, 32);
        __shared__ float ps[4];
        if ((tid & 63) == 0) ps[tid >> 6] = s;
        __syncthreads();
        const float tot = ps[0] + ps[1] + ps[2] + ps[3];
        y *= rsqrtf(tot + 1e-6f);
    }
    outp[(long)bt * KDIM + c] = y;
}

// ---------------------------------------------------------------------------
// DPP 16-lane row sum (reduce group = 16 consecutive lanes = one DPP row).
// quad_perm xor1 (0xB1), quad_perm xor2 (0x4E), row_half_mirror (0x141),
// row_mirror (0x140). Pure-VALU, ~8cy/level vs ~30cy for LDS-path shuffles.
// ---------------------------------------------------------------------------
template<int CTRL>
__device__ __forceinline__ float dppadd(float x) {
    int y = __builtin_amdgcn_update_dpp(0, __float_as_int(x), CTRL, 0xf, 0xf, true);
    return x + __int_as_float(y);
}
__device__ __forceinline__ float rowsum16(float x) {
    x = dppadd<0xB1>(x);
    x = dppadd<0x4E>(x);
    x = dppadd<0x141>(x);
    x = dppadd<0x140>(x);
    return x;
}

// ---------------------------------------------------------------------------
// Sequential gated delta-rule scan, split by state columns.
// grid (12, 16): (b*H+h, v-slice of 16 cols). 256 threads = 4 waves.
// Lane layout: kg = l&15 (k-group; DPP-row reduce), colsub = l>>4.
// 3-deep register pipeline: loads for t+3 issued while computing t
// (~2 iters of latency cover ~ L2 latency). eg input is exp(g).
// ---------------------------------------------------------------------------
struct Tok {
    f4 k0, k1, k2, k3, q0, q1, q2, q3;
    float v, g, b;
};

__global__ __launch_bounds__(256)
void scan_kernel(const float* __restrict__ q, const float* __restrict__ k,
                 const float* __restrict__ v, const float* __restrict__ eg,
                 const float* __restrict__ beta, float* __restrict__ o) {
    const int bh = blockIdx.x;
    const int b = bh / NHEADS, h = bh % NHEADS;
    const int tid = threadIdx.x;
    const int w = tid >> 6, l = tid & 63;
    const int colsub = l >> 4;             // 0..3
    const int kg = l & 15;                 // 0..15
    const int col = blockIdx.y * 16 + w * 4 + colsub;
    float S0[4] = {}, S1[4] = {}, S2[4] = {}, S3[4] = {};

    const long base = (long)b * SEQ * KDIM + (long)h * HDIM;
    const float* kp = k + base + kg * 16;
    const float* qp = q + base + kg * 16;
    const float* vp = v + base + col;
    const float* gp = eg   + (long)b * SEQ * NHEADS + h;
    const float* bp = beta + (long)b * SEQ * NHEADS + h;
    float* outp = o + base + col;

#define LOADTOK(dst, tt) { \
    const long _o = (long)(tt) * KDIM; \
    const long _s = (long)(tt) * NHEADS; \
    dst.k0 = *(const f4*)(kp + _o);      dst.k1 = *(const f4*)(kp + _o + 4); \
    dst.k2 = *(const f4*)(kp + _o + 8);  dst.k3 = *(const f4*)(kp + _o + 12); \
    dst.q0 = *(const f4*)(qp + _o);      dst.q1 = *(const f4*)(qp + _o + 4); \
    dst.q2 = *(const f4*)(qp + _o + 8);  dst.q3 = *(const f4*)(qp + _o + 12); \
    dst.v = vp[_o]; dst.g = gp[_s]; dst.b = bp[_s]; }

#define STEP(BUF, tc) { \
    const int _lt = ((tc) + 3 < SEQ) ? ((tc) + 3) : (SEQ - 1); \
    Tok _nb; LOADTOK(_nb, _lt); \
    const float _cg = BUF.g; \
    float _p0 = 0.f, _p1 = 0.f, _p2 = 0.f, _p3 = 0.f; \
    _Pragma("unroll") \
    for (int j = 0; j < 4; ++j) { \
        S0[j] *= _cg; _p0 += BUF.k0[j] * S0[j]; \
        S1[j] *= _cg; _p1 += BUF.k1[j] * S1[j]; \
        S2[j] *= _cg; _p2 += BUF.k2[j] * S2[j]; \
        S3[j] *= _cg; _p3 += BUF.k3[j] * S3[j]; } \
    float _kv = rowsum16((_p0 + _p1) + (_p2 + _p3)); \
    const float _u = BUF.b * (BUF.v - _kv); \
    float _o0 = 0.f, _o1 = 0.f, _o2 = 0.f, _o3 = 0.f; \
    _Pragma("unroll") \
    for (int j = 0; j < 4; ++j) { \
        S0[j] += BUF.k0[j] * _u; _o0 += BUF.q0[j] * S0[j]; \
        S1[j] += BUF.k1[j] * _u; _o1 += BUF.q1[j] * S1[j]; \
        S2[j] += BUF.k2[j] * _u; _o2 += BUF.q2[j] * S2[j]; \
        S3[j] += BUF.k3[j] * _u; _o3 += BUF.q3[j] * S3[j]; } \
    float _op = rowsum16((_o0 + _o1) + (_o2 + _o3)); \
    if (kg == 0) outp[(long)(tc) * KDIM] = _op * 0.0625f; \
    BUF = _nb; }

    Tok A, Bk, Ck;
    LOADTOK(A, 0); LOADTOK(Bk, 1); LOADTOK(Ck, 2);

    for (int t = 0; t < SEQ - 2; t += 3) {
        STEP(A, t); STEP(Bk, t + 1); STEP(Ck, t + 2);
    }
    // SEQ = 2048 = 3*682 + 2 -> tail steps 2046, 2047
    STEP(A, SEQ - 2);
    STEP(Bk, SEQ - 1);
#undef STEP
#undef LOADTOK
}

// ---------------------------------------------------------------------------
// o = rmsnorm(o)*w * silu(gate)
// ---------------------------------------------------------------------------
__global__ __launch_bounds__(256)
void norm_gate(const float* __restrict__ o, const float* __restrict__ gate,
               const float* __restrict__ nw, float* __restrict__ on) {
    const int bt = blockIdx.x, h = blockIdx.y, d = threadIdx.x;
    const long idx = (long)bt * KDIM + h * HDIM + d;
    const float ov = o[idx];
    float s = ov * ov;
    s += __shfl_xor(s, 1);  s += __shfl_xor(s, 2);  s += __shfl_xor(s, 4);
    s += __shfl_xor(s, 8);  s += __shfl_xor(s, 16); s += __shfl_xor(s, 32);
    __shared__ float ps[4];
    if ((d & 63) == 0) ps[d >> 6] = s;
    __syncthreads();
    const float tot = ps[0] + ps[1] + ps[2] + ps[3];
    const float r = rsqrtf(tot * (1.f / HDIM) + 1e-5f);
    const float gv = gate[idx];
    on[idx] = ov * r * nw[d] * (gv / (1.f + expf(-gv)));
}

// ---------------------------------------------------------------------------
extern "C" void kernel_launch(void* const* d_in, const int* in_sizes, int n_in,
                              void* d_out, int out_size, void* d_ws, size_t ws_size,
                              hipStream_t stream) {
    const float* x       = (const float*)d_in[0];
    const float* Wq      = (const float*)d_in[1];
    const float* Wk      = (const float*)d_in[2];
    const float* Wv      = (const float*)d_in[3];
    const float* Wo      = (const float*)d_in[4];
    const float* Wb      = (const float*)d_in[5];
    const float* Wa      = (const float*)d_in[6];
    const float* Wg      = (const float*)d_in[7];
    const float* conv_q  = (const float*)d_in[8];
    const float* conv_k  = (const float*)d_in[9];
    const float* conv_v  = (const float*)d_in[10];
    const float* o_norm_w= (const float*)d_in[11];
    const float* A_log   = (const float*)d_in[12];
    const float* dt_bias = (const float*)d_in[13];
    float* out = (float*)d_out;

    // ---- workspace layout ----
    const size_t SZ  = (size_t)BT * KDIM;      // 6.29M  (proj output)
    const size_t XSZ = (size_t)BT * HIDDEN;    // 8.39M  (x)
    const size_t WSZ = (size_t)KDIM * HIDDEN;  // 3.15M  (one proj weight)
    float* ws   = (float*)d_ws;
    float* qraw = ws;
    float* kraw = qraw + SZ;
    float* vraw = kraw + SZ;
    float* graw = vraw + SZ;
    float* qn   = graw + SZ;
    float* kn   = qn + SZ;
    float* vn   = kn + SZ;
    float* beta = vn + SZ;                      // BT*NHEADS = 24576
    float* gdec = beta + (size_t)BT * NHEADS;
    u16* bs = (u16*)(gdec + (size_t)BT * NHEADS);
    u16* xh = bs;
    u16* xl = xh + XSZ;
    u16* wh = xl + XSZ;                         // Wq,Wk,Wv,Wg hi (4*WSZ)
    u16* wl = wh + 4 * WSZ;                     // lo
    // aliases (used after projections are consumed):
    u16* onh = bs;                              // onrm hi (SZ)
    u16* onl = onh + SZ;                        // onrm lo
    u16* woh = onl + SZ;                        // Wo hi (WSZ)
    u16* wol = woh + WSZ;                       // Wo lo
    float* obuf = qraw;                         // scan output (qraw dead)
    float* onrm = kraw;                         // normed output (kraw dead)

    dim3 blk(256);
    // ---- split inputs to bf16 hi/lo ----
    split_bf16<<<dim3(2048), blk, 0, stream>>>(x,  xh, xl, (int)(XSZ / 4));
    split_bf16<<<dim3(2048), blk, 0, stream>>>(Wq, wh + 0 * WSZ, wl + 0 * WSZ, (int)(WSZ / 4));
    split_bf16<<<dim3(2048), blk, 0, stream>>>(Wk, wh + 1 * WSZ, wl + 1 * WSZ, (int)(WSZ / 4));
    split_bf16<<<dim3(2048), blk, 0, stream>>>(Wv, wh + 2 * WSZ, wl + 2 * WSZ, (int)(WSZ / 4));
    split_bf16<<<dim3(2048), blk, 0, stream>>>(Wg, wh + 3 * WSZ, wl + 3 * WSZ, (int)(WSZ / 4));
    // ---- fused q/k/v/gate projections ----
    gemm_bf16_split<<<dim3(BT / GBM, 48), blk, 0, stream>>>(
        xh, xl, wh, wl, qraw, HIDDEN, KDIM, 12);
    // ---- beta / exp(g) ----
    beta_g_kernel<<<dim3(BT), blk, 0, stream>>>(x, Wb, Wa, A_log, dt_bias, beta, gdec);
    // ---- conv + silu (+ l2norm for q,k) ----
    conv_silu_norm<<<dim3(BT, NHEADS), blk, 0, stream>>>(qraw, conv_q, qn, 1);
    conv_silu_norm<<<dim3(BT, NHEADS), blk, 0, stream>>>(kraw, conv_k, kn, 1);
    conv_silu_norm<<<dim3(BT, NHEADS), blk, 0, stream>>>(vraw, conv_v, vn, 0);
    // ---- sequential delta-rule scan ----
    scan_kernel<<<dim3(BATCH * NHEADS, 16), blk, 0, stream>>>(qn, kn, vn, gdec, beta, obuf);
    // ---- rmsnorm * w * silu(gate) ----
    norm_gate<<<dim3(BT, NHEADS), blk, 0, stream>>>(obuf, graw, o_norm_w, onrm);
    // ---- output projection ----
    split_bf16<<<dim3(2048), blk, 0, stream>>>(onrm, onh, onl, (int)(SZ / 4));
    split_bf16<<<dim3(2048), blk, 0, stream>>>(Wo, woh, wol, (int)(WSZ / 4));
    gemm_bf16_split<<<dim3(BT / GBM, 16), blk, 0, stream>>>(
        onh, onl, woh, wol, out, KDIM, HIDDEN, 16);
}

// Round 7
// 1507.653 us; speedup vs baseline: 1.5855x; 1.1296x over previous
//
#include <hip/hip_runtime.h>
#include <hip/hip_bf16.h>
#include <math.h>
#include <stdint.h>

#define HIDDEN 2048
#define NHEADS 6
#define HDIM 256
#define KDIM 1536
#define BATCH 2
#define SEQ 2048
#define BT (BATCH*SEQ)

typedef unsigned short u16;
typedef __attribute__((ext_vector_type(8))) short bf16x8;
typedef __attribute__((ext_vector_type(4))) float f32x4;
typedef __attribute__((ext_vector_type(4))) float f4;

__device__ __forceinline__ u16 f2bf(float f) {
    unsigned u = __float_as_uint(f);
    u += 0x7FFFu + ((u >> 16) & 1u);          // round to nearest even
    return (u16)(u >> 16);
}
__device__ __forceinline__ float bf2f(u16 h) {
    return __uint_as_float(((unsigned)h) << 16);
}

// ---------------------------------------------------------------------------
// fp32 -> (bf16 hi, bf16 lo) split:  x ~= hi + lo  (lo captures next 8 bits)
// ---------------------------------------------------------------------------
__global__ __launch_bounds__(256)
void split_bf16(const float* __restrict__ src, u16* __restrict__ hi,
                u16* __restrict__ lo, int n4) {
    const int stride = gridDim.x * 256;
    for (int i = blockIdx.x * 256 + threadIdx.x; i < n4; i += stride) {
        const float4 f = ((const float4*)src)[i];
        ushort4 h, l;
        h.x = f2bf(f.x); l.x = f2bf(f.x - bf2f(h.x));
        h.y = f2bf(f.y); l.y = f2bf(f.y - bf2f(h.y));
        h.z = f2bf(f.z); l.z = f2bf(f.z - bf2f(h.z));
        h.w = f2bf(f.w); l.w = f2bf(f.w - bf2f(h.w));
        ((ushort4*)hi)[i] = h;
        ((ushort4*)lo)[i] = l;
    }
}

// ---------------------------------------------------------------------------
// Split-bf16 MFMA GEMM:  C[M=4096, N] = A[M,K] @ B[N,K]^T  (3-term split)
// 128x128 tile, BK=64, 4 waves, global_load_lds staging with XOR slot swizzle
// applied on the *global source* address (linear LDS dest) and on ds_read.
// ---------------------------------------------------------------------------
#define GBM 128
#define GBK 64

#define GLL(gp, lp) __builtin_amdgcn_global_load_lds( \
    (__attribute__((address_space(1))) void*)(gp), \
    (__attribute__((address_space(3))) void*)(lp), 16, 0, 0)

__global__ __launch_bounds__(256, 2)
void gemm_bf16_split(const u16* __restrict__ Ah, const u16* __restrict__ Al,
                     const u16* __restrict__ Bh0, const u16* __restrict__ Bl0,
                     float* __restrict__ C0, int K, int rowsPerW, int blocksPerW) {
    __shared__ u16 lAh[GBM * GBK];
    __shared__ u16 lAl[GBM * GBK];
    __shared__ u16 lBh[GBM * GBK];
    __shared__ u16 lBl[GBM * GBK];

    const int j  = blockIdx.y / blocksPerW;
    const int ny = blockIdx.y % blocksPerW;
    const int m0 = blockIdx.x * GBM;
    const int n0 = ny * GBM;
    const u16* Bh = Bh0 + (size_t)j * rowsPerW * K;
    const u16* Bl = Bl0 + (size_t)j * rowsPerW * K;
    float* C = C0 + (size_t)j * (size_t)BT * rowsPerW;

    const int tid = threadIdx.x;
    const int wv  = tid >> 6;
    const int ln  = tid & 63;
    const int lr8 = ln >> 3;               // row within 8-row chunk
    const int lsl = (ln & 7) ^ lr8;        // pre-swizzled source slot

    const u16* pAh[4]; const u16* pAl[4]; const u16* pBh[4]; const u16* pBl[4];
    u16* dAh[4]; u16* dAl[4]; u16* dBh[4]; u16* dBl[4];
    #pragma unroll
    for (int u = 0; u < 4; ++u) {
        const int c = wv * 4 + u;
        const size_t ra = (size_t)(m0 + c * 8 + lr8) * K + (size_t)lsl * 8;
        const size_t rb = (size_t)(n0 + c * 8 + lr8) * K + (size_t)lsl * 8;
        pAh[u] = Ah + ra; pAl[u] = Al + ra;
        pBh[u] = Bh + rb; pBl[u] = Bl + rb;
        dAh[u] = &lAh[c * 512]; dAl[u] = &lAl[c * 512];
        dBh[u] = &lBh[c * 512]; dBl[u] = &lBl[c * 512];
    }

    const int lane15 = ln & 15;
    const int l16 = ln >> 4;               // 0..3 (k-slot within MFMA)
    const int wm = (wv >> 1) * 64;
    const int wn = (wv & 1) * 64;
    const int rA = wm + lane15;
    const int rB = wn + lane15;
    const int xA = rA & 7;
    const int xB = rB & 7;

    f32x4 acc[4][4] = {};

    for (int k0 = 0; k0 < K; k0 += GBK) {
        #pragma unroll
        for (int u = 0; u < 4; ++u) {
            GLL(pAh[u] + k0, dAh[u]);
            GLL(pAl[u] + k0, dAl[u]);
            GLL(pBh[u] + k0, dBh[u]);
            GLL(pBl[u] + k0, dBl[u]);
        }
        __syncthreads();
        #pragma unroll
        for (int kh = 0; kh < 2; ++kh) {
            bf16x8 a_h[4], a_l[4], b_h[4], b_l[4];
            #pragma unroll
            for (int mi = 0; mi < 4; ++mi) {
                const int off = (rA + mi * 16) * GBK + ((((kh << 2) | l16)) ^ xA) * 8;
                a_h[mi] = *(const bf16x8*)&lAh[off];
                a_l[mi] = *(const bf16x8*)&lAl[off];
            }
            #pragma unroll
            for (int ni = 0; ni < 4; ++ni) {
                const int off = (rB + ni * 16) * GBK + ((((kh << 2) | l16)) ^ xB) * 8;
                b_h[ni] = *(const bf16x8*)&lBh[off];
                b_l[ni] = *(const bf16x8*)&lBl[off];
            }
            #pragma unroll
            for (int mi = 0; mi < 4; ++mi)
                #pragma unroll
                for (int ni = 0; ni < 4; ++ni) {
                    acc[mi][ni] = __builtin_amdgcn_mfma_f32_16x16x32_bf16(a_h[mi], b_h[ni], acc[mi][ni], 0, 0, 0);
                    acc[mi][ni] = __builtin_amdgcn_mfma_f32_16x16x32_bf16(a_h[mi], b_l[ni], acc[mi][ni], 0, 0, 0);
                    acc[mi][ni] = __builtin_amdgcn_mfma_f32_16x16x32_bf16(a_l[mi], b_h[ni], acc[mi][ni], 0, 0, 0);
                }
        }
        __syncthreads();
    }

    #pragma unroll
    for (int mi = 0; mi < 4; ++mi)
        #pragma unroll
        for (int ni = 0; ni < 4; ++ni) {
            const int m = m0 + wm + mi * 16 + l16 * 4;
            const int n = n0 + wn + ni * 16 + lane15;
            #pragma unroll
            for (int r = 0; r < 4; ++r)
                C[(size_t)(m + r) * rowsPerW + n] = acc[mi][ni][r];
        }
}

// ---------------------------------------------------------------------------
// beta = sigmoid(x @ Wb^T), eg = exp(-exp(A_log)*softplus(x @ Wa^T + dt_bias))
// Stores exp(g): keeps the transcendental OFF the scan's critical path.
// ---------------------------------------------------------------------------
__global__ __launch_bounds__(256)
void beta_g_kernel(const float* __restrict__ x, const float* __restrict__ Wb,
                   const float* __restrict__ Wa, const float* __restrict__ A_log,
                   const float* __restrict__ dt_bias,
                   float* __restrict__ beta, float* __restrict__ eg) {
    const int bt = blockIdx.x;
    __shared__ float xs[HIDDEN];
    const int tid = threadIdx.x;
    for (int i = tid; i < HIDDEN; i += 256) xs[i] = x[(long)bt * HIDDEN + i];
    __syncthreads();
    const int w = tid >> 6, l = tid & 63;
    #pragma unroll
    for (int r = 0; r < 3; ++r) {
        const int dj = w * 3 + r;  // 0..11
        const float* Wrow = (dj < 6) ? (Wb + dj * HIDDEN) : (Wa + (dj - 6) * HIDDEN);
        float s = 0.f;
        for (int i = l; i < HIDDEN; i += 64) s += xs[i] * Wrow[i];
        s += __shfl_xor(s, 1);  s += __shfl_xor(s, 2);  s += __shfl_xor(s, 4);
        s += __shfl_xor(s, 8);  s += __shfl_xor(s, 16); s += __shfl_xor(s, 32);
        if (l == 0) {
            if (dj < 6) {
                beta[bt * NHEADS + dj] = 1.f / (1.f + expf(-s));
            } else {
                const int h = dj - 6;
                const float z = s + dt_bias[h];
                const float sp = fmaxf(z, 0.f) + log1pf(expf(-fabsf(z)));
                eg[bt * NHEADS + h] = expf(-expf(A_log[h]) * sp);
            }
        }
    }
}

// ---------------------------------------------------------------------------
// causal depthwise conv (K=4) + SiLU, optional per-head L2 norm.
// ---------------------------------------------------------------------------
__global__ __launch_bounds__(256)
void conv_silu_norm(const float* __restrict__ raw, const float* __restrict__ cw,
                    float* __restrict__ outp, int do_norm) {
    const int bt = blockIdx.x;
    const int h  = blockIdx.y;
    const int t  = bt & (SEQ - 1);
    const int tid = threadIdx.x;
    const int c = h * HDIM + tid;
    const float4 w4 = *(const float4*)(cw + (long)c * 4);
    const float* rp = raw + (long)bt * KDIM + c;
    float y;
    if (t >= 3) {
        y = rp[-3 * KDIM] * w4.x + rp[-2 * KDIM] * w4.y + rp[-KDIM] * w4.z + rp[0] * w4.w;
    } else {
        y = rp[0] * w4.w;
        if (t >= 1) y += rp[-KDIM] * w4.z;
        if (t >= 2) y += rp[-2 * KDIM] * w4.y;
    }
    y = y / (1.f + expf(-y));  // SiLU
    if (do_norm) {
        float s = y * y;
        s += __shfl_xor(s, 1);  s += __shfl_xor(s, 2);  s += __shfl_xor(s, 4);
        s += __shfl_xor(s, 8);  s += __shfl_xor(s, 16); s += __shfl_xor(s, 32);
        __shared__ float ps[4];
        if ((tid & 63) == 0) ps[tid >> 6] = s;
        __syncthreads();
        const float tot = ps[0] + ps[1] + ps[2] + ps[3];
        y *= rsqrtf(tot + 1e-6f);
    }
    outp[(long)bt * KDIM + c] = y;
}

// ---------------------------------------------------------------------------
// DPP 16-lane row sum (reduce group = 16 consecutive lanes = one DPP row).
// ---------------------------------------------------------------------------
template<int CTRL>
__device__ __forceinline__ float dppadd(float x) {
    int y = __builtin_amdgcn_update_dpp(0, __float_as_int(x), CTRL, 0xf, 0xf, true);
    return x + __int_as_float(y);
}
__device__ __forceinline__ float rowsum16(float x) {
    x = dppadd<0xB1>(x);
    x = dppadd<0x4E>(x);
    x = dppadd<0x141>(x);
    x = dppadd<0x140>(x);
    return x;
}

// ---------------------------------------------------------------------------
// Sequential gated delta-rule scan, split by state columns.
// grid (12, 16): (b*H+h, v-slice of 16 cols). 256 threads = 4 waves.
// Lane layout: kg = l&15 (k-group; DPP-row reduce), colsub = l>>4.
// TRUE 4-deep rotating pipeline: 4 named buffers, unroll-by-4, loads for
// t+4 issued AFTER compute of t, first used 3 steps later -> counted vmcnt.
// f4 vector arithmetic -> v_pk_fma_f32 (2 fp32/instr) halves VALU issue.
// Carried chain: kv = cg*(k.S_old), S = fma(k, u, cg*S).
// ---------------------------------------------------------------------------
struct Tok {
    f4 k0, k1, k2, k3, q0, q1, q2, q3;
    float v, g, b;
};

__global__ __launch_bounds__(256, 1)
void scan_kernel(const float* __restrict__ q, const float* __restrict__ k,
                 const float* __restrict__ v, const float* __restrict__ eg,
                 const float* __restrict__ beta, float* __restrict__ o) {
    const int bh = blockIdx.x;
    const int b = bh / NHEADS, h = bh % NHEADS;
    const int tid = threadIdx.x;
    const int w = tid >> 6, l = tid & 63;
    const int colsub = l >> 4;             // 0..3
    const int kg = l & 15;                 // 0..15
    const int col = blockIdx.y * 16 + w * 4 + colsub;
    f4 S0 = {0,0,0,0}, S1 = {0,0,0,0}, S2 = {0,0,0,0}, S3 = {0,0,0,0};

    const long base = (long)b * SEQ * KDIM + (long)h * HDIM;
    const float* kp = k + base + kg * 16;
    const float* qp = q + base + kg * 16;
    const float* vp = v + base + col;
    const float* gp = eg   + (long)b * SEQ * NHEADS + h;
    const float* bp = beta + (long)b * SEQ * NHEADS + h;
    float* outp = o + base + col;

#define LOADTOK(dst, tt) { \
    const int _t = ((tt) < SEQ) ? (tt) : (SEQ - 1); \
    const long _o = (long)_t * KDIM; \
    const long _s = (long)_t * NHEADS; \
    dst.k0 = *(const f4*)(kp + _o);      dst.k1 = *(const f4*)(kp + _o + 4); \
    dst.k2 = *(const f4*)(kp + _o + 8);  dst.k3 = *(const f4*)(kp + _o + 12); \
    dst.q0 = *(const f4*)(qp + _o);      dst.q1 = *(const f4*)(qp + _o + 4); \
    dst.q2 = *(const f4*)(qp + _o + 8);  dst.q3 = *(const f4*)(qp + _o + 12); \
    dst.v = vp[_o]; dst.g = gp[_s]; dst.b = bp[_s]; }

#define STEP(BUF, tc) { \
    const float _cg = BUF.g; \
    const f4 _cg4 = {_cg, _cg, _cg, _cg}; \
    const f4 _d0 = _cg4 * S0, _d1 = _cg4 * S1, _d2 = _cg4 * S2, _d3 = _cg4 * S3; \
    f4 _pa = BUF.k0 * S0 + BUF.k1 * S1; \
    f4 _pb = BUF.k2 * S2 + BUF.k3 * S3; \
    _pa = _pa + _pb; \
    const float _p = (_pa.x + _pa.y) + (_pa.z + _pa.w); \
    const float _kv = _cg * rowsum16(_p); \
    const float _u = BUF.b * (BUF.v - _kv); \
    const f4 _u4 = {_u, _u, _u, _u}; \
    S0 = BUF.k0 * _u4 + _d0; S1 = BUF.k1 * _u4 + _d1; \
    S2 = BUF.k2 * _u4 + _d2; S3 = BUF.k3 * _u4 + _d3; \
    f4 _oa = BUF.q0 * S0 + BUF.q1 * S1; \
    f4 _ob = BUF.q2 * S2 + BUF.q3 * S3; \
    _oa = _oa + _ob; \
    const float _oo = (_oa.x + _oa.y) + (_oa.z + _oa.w); \
    const float _op = rowsum16(_oo); \
    if (kg == 0) outp[(long)(tc) * KDIM] = _op * 0.0625f; }

    Tok A, B, C, D;
    LOADTOK(A, 0); LOADTOK(B, 1); LOADTOK(C, 2); LOADTOK(D, 3);

    for (int t = 0; t < SEQ; t += 4) {
        STEP(A, t);     LOADTOK(A, t + 4);
        STEP(B, t + 1); LOADTOK(B, t + 5);
        STEP(C, t + 2); LOADTOK(C, t + 6);
        STEP(D, t + 3); LOADTOK(D, t + 7);
    }
#undef STEP
#undef LOADTOK
}

// ---------------------------------------------------------------------------
// o = rmsnorm(o)*w * silu(gate)
// ---------------------------------------------------------------------------
__global__ __launch_bounds__(256)
void norm_gate(const float* __restrict__ o, const float* __restrict__ gate,
               const float* __restrict__ nw, float* __restrict__ on) {
    const int bt = blockIdx.x, h = blockIdx.y, d = threadIdx.x;
    const long idx = (long)bt * KDIM + h * HDIM + d;
    const float ov = o[idx];
    float s = ov * ov;
    s += __shfl_xor(s, 1);  s += __shfl_xor(s, 2);  s += __shfl_xor(s, 4);
    s += __shfl_xor(s, 8);  s += __shfl_xor(s, 16); s += __shfl_xor(s, 32);
    __shared__ float ps[4];
    if ((d & 63) == 0) ps[d >> 6] = s;
    __syncthreads();
    const float tot = ps[0] + ps[1] + ps[2] + ps[3];
    const float r = rsqrtf(tot * (1.f / HDIM) + 1e-5f);
    const float gv = gate[idx];
    on[idx] = ov * r * nw[d] * (gv / (1.f + expf(-gv)));
}

// ---------------------------------------------------------------------------
extern "C" void kernel_launch(void* const* d_in, const int* in_sizes, int n_in,
                              void* d_out, int out_size, void* d_ws, size_t ws_size,
                              hipStream_t stream) {
    const float* x       = (const float*)d_in[0];
    const float* Wq      = (const float*)d_in[1];
    const float* Wk      = (const float*)d_in[2];
    const float* Wv      = (const float*)d_in[3];
    const float* Wo      = (const float*)d_in[4];
    const float* Wb      = (const float*)d_in[5];
    const float* Wa      = (const float*)d_in[6];
    const float* Wg      = (const float*)d_in[7];
    const float* conv_q  = (const float*)d_in[8];
    const float* conv_k  = (const float*)d_in[9];
    const float* conv_v  = (const float*)d_in[10];
    const float* o_norm_w= (const float*)d_in[11];
    const float* A_log   = (const float*)d_in[12];
    const float* dt_bias = (const float*)d_in[13];
    float* out = (float*)d_out;

    // ---- workspace layout ----
    const size_t SZ  = (size_t)BT * KDIM;      // 6.29M  (proj output)
    const size_t XSZ = (size_t)BT * HIDDEN;    // 8.39M  (x)
    const size_t WSZ = (size_t)KDIM * HIDDEN;  // 3.15M  (one proj weight)
    float* ws   = (float*)d_ws;
    float* qraw = ws;
    float* kraw = qraw + SZ;
    float* vraw = kraw + SZ;
    float* graw = vraw + SZ;
    float* qn   = graw + SZ;
    float* kn   = qn + SZ;
    float* vn   = kn + SZ;
    float* beta = vn + SZ;                      // BT*NHEADS = 24576
    float* gdec = beta + (size_t)BT * NHEADS;
    u16* bs = (u16*)(gdec + (size_t)BT * NHEADS);
    u16* xh = bs;
    u16* xl = xh + XSZ;
    u16* wh = xl + XSZ;                         // Wq,Wk,Wv,Wg hi (4*WSZ)
    u16* wl = wh + 4 * WSZ;                     // lo
    // aliases (used after projections are consumed):
    u16* onh = bs;                              // onrm hi (SZ)
    u16* onl = onh + SZ;                        // onrm lo
    u16* woh = onl + SZ;                        // Wo hi (WSZ)
    u16* wol = woh + WSZ;                       // Wo lo
    float* obuf = qraw;                         // scan output (qraw dead)
    float* onrm = kraw;                         // normed output (kraw dead)

    dim3 blk(256);
    // ---- split inputs to bf16 hi/lo ----
    split_bf16<<<dim3(2048), blk, 0, stream>>>(x,  xh, xl, (int)(XSZ / 4));
    split_bf16<<<dim3(2048), blk, 0, stream>>>(Wq, wh + 0 * WSZ, wl + 0 * WSZ, (int)(WSZ / 4));
    split_bf16<<<dim3(2048), blk, 0, stream>>>(Wk, wh + 1 * WSZ, wl + 1 * WSZ, (int)(WSZ / 4));
    split_bf16<<<dim3(2048), blk, 0, stream>>>(Wv, wh + 2 * WSZ, wl + 2 * WSZ, (int)(WSZ / 4));
    split_bf16<<<dim3(2048), blk, 0, stream>>>(Wg, wh + 3 * WSZ, wl + 3 * WSZ, (int)(WSZ / 4));
    // ---- fused q/k/v/gate projections ----
    gemm_bf16_split<<<dim3(BT / GBM, 48), blk, 0, stream>>>(
        xh, xl, wh, wl, qraw, HIDDEN, KDIM, 12);
    // ---- beta / exp(g) ----
    beta_g_kernel<<<dim3(BT), blk, 0, stream>>>(x, Wb, Wa, A_log, dt_bias, beta, gdec);
    // ---- conv + silu (+ l2norm for q,k) ----
    conv_silu_norm<<<dim3(BT, NHEADS), blk, 0, stream>>>(qraw, conv_q, qn, 1);
    conv_silu_norm<<<dim3(BT, NHEADS), blk, 0, stream>>>(kraw, conv_k, kn, 1);
    conv_silu_norm<<<dim3(BT, NHEADS), blk, 0, stream>>>(vraw, conv_v, vn, 0);
    // ---- sequential delta-rule scan ----
    scan_kernel<<<dim3(BATCH * NHEADS, 16), blk, 0, stream>>>(qn, kn, vn, gdec, beta, obuf);
    // ---- rmsnorm * w * silu(gate) ----
    norm_gate<<<dim3(BT, NHEADS), blk, 0, stream>>>(obuf, graw, o_norm_w, onrm);
    // ---- output projection ----
    split_bf16<<<dim3(2048), blk, 0, stream>>>(onrm, onh, onl, (int)(SZ / 4));
    split_bf16<<<dim3(2048), blk, 0, stream>>>(Wo, woh, wol, (int)(WSZ / 4));
    gemm_bf16_split<<<dim3(BT / GBM, 16), blk, 0, stream>>>(
        onh, onl, woh, wol, out, KDIM, HIDDEN, 16);
}